// Round 8
// baseline (394.184 us; speedup 1.0000x reference)
//
#include <hip/hip_runtime.h>
#include <hip/hip_bf16.h>

// Problem constants (B=4,T=16,N=64,D=256, H=4 heads, hd=64) — all fp32 I/O
#define BATCH 64          // B*T
#define NRES 64           // N
#define DMODEL 256        // D
#define ROWS (BATCH*NRES) // 4096
#define QKVC 768          // 3*D
#define SCALE 0.125f      // 1/sqrt(64)
#define LDP 68            // padded LDS leading dim: b128-aligned, conflict-benign

// native clang vector type — accepted by __builtin_nontemporal_load
typedef float floatx4 __attribute__((ext_vector_type(4)));

// ---------------------------------------------------------------------------
// Kernel 1: qkv = x @ Wqkv + bqkv.  (4096x256)@(256x768) fp32, 64x64 tiles.
// A staged transposed (AsT[c][r], stride 68) -> A-fragment = one ds_read_b128.
// (R6 evidence: not LDS-bound; leave structure alone.)
// ---------------------------------------------------------------------------
__global__ __launch_bounds__(256) void qkv_gemm(
    const float* __restrict__ x, const float* __restrict__ W,
    const float* __restrict__ bq, float* __restrict__ qkv) {
  __shared__ float AsT[64 * LDP];  // [c][r]
  __shared__ float Bs[64 * LDP];   // [r][c]
  int t = threadIdx.x;
  int tx = t & 15, ty = t >> 4;
  int rowBase = blockIdx.y * 64;
  int colBase = blockIdx.x * 64;
  float acc[4][4] = {};
  for (int kb = 0; kb < 256; kb += 64) {
#pragma unroll
    for (int p = 0; p < 4; ++p) {
      int e = (p * 256 + t) * 4;
      int r = e >> 6, c = e & 63;
      float4 av = *(const float4*)&x[(size_t)(rowBase + r) * 256 + kb + c];
      AsT[(c + 0) * LDP + r] = av.x;
      AsT[(c + 1) * LDP + r] = av.y;
      AsT[(c + 2) * LDP + r] = av.z;
      AsT[(c + 3) * LDP + r] = av.w;
      *(float4*)&Bs[r * LDP + c] =
          *(const float4*)&W[(size_t)(kb + r) * QKVC + colBase + c];
    }
    __syncthreads();
#pragma unroll 4
    for (int kk = 0; kk < 64; ++kk) {
      float4 a4 = *(const float4*)&AsT[kk * LDP + ty * 4];
      float4 b4 = *(const float4*)&Bs[kk * LDP + tx * 4];
      float a[4] = {a4.x, a4.y, a4.z, a4.w};
      float b[4] = {b4.x, b4.y, b4.z, b4.w};
#pragma unroll
      for (int i = 0; i < 4; ++i)
#pragma unroll
        for (int j = 0; j < 4; ++j) acc[i][j] += a[i] * b[j];
    }
    __syncthreads();
  }
#pragma unroll
  for (int i = 0; i < 4; ++i) {
    int r = rowBase + ty * 4 + i;
#pragma unroll
    for (int j = 0; j < 4; ++j) {
      int c = colBase + tx * 4 + j;
      qkv[(size_t)r * QKVC + c] = acc[i][j] + bq[c];
    }
  }
}

// ---------------------------------------------------------------------------
// Kernel 2: fused qk + rel + softmax + AV, one block per (b,n).
// Proven R6 lane map: wave handles rows mm = 4i+wave; 64 lanes read a full
// contiguous 1KB row per instruction (bias from HBM nontemporal, k from
// L2-hot qkv ws). Lane covers channels [lane*4, lane*4+4); 16-lane segment
// reduce (shfl_xor 1,2,4,8) per stream -> per-head dot for the row.
// qk dot runs for ALL rows (reference adds qk*scale even when masked);
// bias dot only for unmasked rows (~50% skipped, wave-uniform branch).
// Replaces the separate qk_gemm kernel + 8MB qk ws round-trip.
// ---------------------------------------------------------------------------
__global__ __launch_bounds__(256) void attn_kernel(
    const float* __restrict__ bias, const int* __restrict__ mask,
    const float* __restrict__ qkv, float* __restrict__ ctx) {
  __shared__ float q_s[256];
  __shared__ int mask_s[64];
  __shared__ float rel_s[256];   // [h][m]
  __shared__ float pk_s[256];    // [h][m]
  __shared__ float attn_s[256];  // [h][m]
  int t = threadIdx.x;
  int blk = blockIdx.x;  // b*64+n
  int b = blk >> 6;
  int m = t & 63, h = t >> 6;
  int msk = mask[b * 64 + m];
  if (t < 64) mask_s[t] = mask[b * 64 + t];
  q_s[t] = qkv[(size_t)blk * QKVC + t];  // q = first 256 cols
  __syncthreads();
  int wave = t >> 6, lane = t & 63;
  int hseg = lane >> 4;  // which head this lane's channels belong to
  float4 qv = *(const float4*)&q_s[lane * 4];
  const floatx4* brow_base = (const floatx4*)(bias + (size_t)blk * 64 * 256);
  const float* kbase = qkv + (size_t)b * 64 * QKVC + 256;  // k rows, stride QKVC
#pragma unroll
  for (int i = 0; i < 16; ++i) {
    int mm = i * 4 + wave;
    // qk dot: k row mm, full-wave contiguous 1KB, L2-hot (reused by 64 blocks)
    floatx4 kv = *(const floatx4*)&kbase[(size_t)mm * QKVC + lane * 4];
    float pk = kv.x * qv.x + kv.y * qv.y + kv.z * qv.z + kv.w * qv.w;
    pk += __shfl_xor(pk, 1, 64);
    pk += __shfl_xor(pk, 2, 64);
    pk += __shfl_xor(pk, 4, 64);
    pk += __shfl_xor(pk, 8, 64);
    if ((lane & 15) == 0) pk_s[hseg * 64 + mm] = pk;
    if (mask_s[mm]) {  // wave-uniform: skip bias row for masked keys
      floatx4 bv = __builtin_nontemporal_load(&brow_base[mm * 64 + lane]);
      float p = bv.x * qv.x + bv.y * qv.y + bv.z * qv.z + bv.w * qv.w;
      p += __shfl_xor(p, 1, 64);
      p += __shfl_xor(p, 2, 64);
      p += __shfl_xor(p, 4, 64);
      p += __shfl_xor(p, 8, 64);
      if ((lane & 15) == 0) rel_s[hseg * 64 + mm] = p;
    }
  }
  __syncthreads();
  float rel = rel_s[h * 64 + m];
  float s_qk = pk_s[h * 64 + m];
  float logit = s_qk * SCALE + (msk ? rel * SCALE : -1e9f);
  // wave-wide (64 lane) softmax over m
  float mx = logit;
#pragma unroll
  for (int off = 32; off > 0; off >>= 1) mx = fmaxf(mx, __shfl_xor(mx, off, 64));
  float ex = __expf(logit - mx);
  float sm = ex;
#pragma unroll
  for (int off = 32; off > 0; off >>= 1) sm += __shfl_xor(sm, off, 64);
  attn_s[h * 64 + m] = ex / sm;
  __syncthreads();
  // AV: thread t = output channel c; head = c>>6 (wave-uniform -> LDS broadcast)
  int c = t;
  int hh = c >> 6;
  float acc = 0.f;
  const float* vbase = qkv + (size_t)b * 64 * QKVC + 512 + c;
#pragma unroll 8
  for (int mm = 0; mm < 64; ++mm) acc += attn_s[hh * 64 + mm] * vbase[(size_t)mm * QKVC];
  ctx[(size_t)blk * 256 + c] = acc;
}

// ---------------------------------------------------------------------------
// Kernel 3: out = ctx @ Wproj + bproj -> fp32. Transposed-A staging.
// ---------------------------------------------------------------------------
__global__ __launch_bounds__(256) void proj_gemm(
    const float* __restrict__ ctx, const float* __restrict__ W,
    const float* __restrict__ bp, float* __restrict__ out) {
  __shared__ float AsT[64 * LDP];
  __shared__ float Bs[64 * LDP];
  int t = threadIdx.x;
  int tx = t & 15, ty = t >> 4;
  int rowBase = blockIdx.y * 64;
  int colBase = blockIdx.x * 64;
  float acc[4][4] = {};
  for (int kb = 0; kb < 256; kb += 64) {
#pragma unroll
    for (int p = 0; p < 4; ++p) {
      int e = (p * 256 + t) * 4;
      int r = e >> 6, c = e & 63;
      float4 av = *(const float4*)&ctx[(size_t)(rowBase + r) * 256 + kb + c];
      AsT[(c + 0) * LDP + r] = av.x;
      AsT[(c + 1) * LDP + r] = av.y;
      AsT[(c + 2) * LDP + r] = av.z;
      AsT[(c + 3) * LDP + r] = av.w;
      *(float4*)&Bs[r * LDP + c] =
          *(const float4*)&W[(size_t)(kb + r) * 256 + colBase + c];
    }
    __syncthreads();
#pragma unroll 4
    for (int kk = 0; kk < 64; ++kk) {
      float4 a4 = *(const float4*)&AsT[kk * LDP + ty * 4];
      float4 b4 = *(const float4*)&Bs[kk * LDP + tx * 4];
      float a[4] = {a4.x, a4.y, a4.z, a4.w};
      float b[4] = {b4.x, b4.y, b4.z, b4.w};
#pragma unroll
      for (int i = 0; i < 4; ++i)
#pragma unroll
        for (int j = 0; j < 4; ++j) acc[i][j] += a[i] * b[j];
    }
    __syncthreads();
  }
#pragma unroll
  for (int i = 0; i < 4; ++i) {
    int r = rowBase + ty * 4 + i;
#pragma unroll
    for (int j = 0; j < 4; ++j) {
      int c = colBase + tx * 4 + j;
      out[(size_t)r * 256 + c] = acc[i][j] + bp[c];
    }
  }
}

extern "C" void kernel_launch(void* const* d_in, const int* in_sizes, int n_in,
                              void* d_out, int out_size, void* d_ws, size_t ws_size,
                              hipStream_t stream) {
  // setup_inputs order: x, bias_features, mask, Wqkv, bqkv, Wproj, bproj
  const float* x    = (const float*)d_in[0];
  const float* bias = (const float*)d_in[1];
  const int*   mask = (const int*)d_in[2];
  const float* Wqkv = (const float*)d_in[3];
  const float* bqkv = (const float*)d_in[4];
  const float* Wprj = (const float*)d_in[5];
  const float* bprj = (const float*)d_in[6];
  float* out = (float*)d_out;

  // workspace layout (fp32): qkv (4096x768) | ctx (4096x256)
  float* qkv_ws = (float*)d_ws;
  float* ctx_ws = qkv_ws + (size_t)ROWS * QKVC;

  qkv_gemm<<<dim3(12, 64), 256, 0, stream>>>(x, Wqkv, bqkv, qkv_ws);
  attn_kernel<<<ROWS, 256, 0, stream>>>(bias, mask, qkv_ws, ctx_ws);
  proj_gemm<<<dim3(4, 64), 256, 0, stream>>>(ctx_ws, Wprj, bprj, out);
}